// Round 4
// baseline (46919.608 us; speedup 1.0000x reference)
//
#include <hip/hip_runtime.h>
#include <math.h>

#define NBLK 256
#define NTHR 256
#define HB 64      // batches per half
#define T_ 512
#define U_ 128
#define N_ 80
#define H_ 512
#define M_ 10
#define KTOT 595   // K order: [h 0..511][w 0..79][x 0..2]

// ---- dynamic-LDS layout (float offsets) ----
#define SM_INPT  0        // 8 buffers x 2048 floats (8 x 8KB) = 65536 B
#define SM_WL    16384    // 9520 floats (38080 B) weight slice, permuted K
#define SM_XLDS  25904    // 192 floats: x rows [3][64]
#define SM_ZBUF  26096    // 1280 floats: z / h-column in stage B
#define SM_CST   27376    // 256 floats: c-state
#define SM_KAP   27632    // 16
#define SM_YL    27648    // 32
#define SM_WF    27680    // 132 (U_+1)
#define SM_WPART 27812    // 160
#define SM_FLOATS 27972
#define SMEM_BYTES (SM_FLOATS * 4)   // 111888 B

typedef __attribute__((address_space(1))) const unsigned int* gp1_t;
typedef __attribute__((address_space(3))) unsigned int* lp3_t;
// width-16 global->LDS DMA: lane i writes ldsbase + i*16, reads gptr + i*16
#define GLOAD16(gp, lp) __builtin_amdgcn_global_load_lds((gp1_t)(gp), (lp3_t)(lp), 16, 0, 0)

// counted DMA wait (waves 0,1 only — they own ALL DMA issues, so N is exact)
#define WAITV(N) do { if (rw < 2) asm volatile("s_waitcnt vmcnt(" #N ")" ::: "memory"); } while (0)
// raw barrier, no vmcnt drain; memory-asm pins LDS reads / DMA issues on both sides
#define BARX()   do { asm volatile("" ::: "memory"); __builtin_amdgcn_s_barrier(); asm volatile("" ::: "memory"); } while (0)

#define FMA16(iv, wv) do { \
    acc[0][0] = fmaf((iv).x, (wv).x, acc[0][0]); acc[0][1] = fmaf((iv).x, (wv).y, acc[0][1]); \
    acc[0][2] = fmaf((iv).x, (wv).z, acc[0][2]); acc[0][3] = fmaf((iv).x, (wv).w, acc[0][3]); \
    acc[1][0] = fmaf((iv).y, (wv).x, acc[1][0]); acc[1][1] = fmaf((iv).y, (wv).y, acc[1][1]); \
    acc[1][2] = fmaf((iv).y, (wv).z, acc[1][2]); acc[1][3] = fmaf((iv).y, (wv).w, acc[1][3]); \
    acc[2][0] = fmaf((iv).z, (wv).x, acc[2][0]); acc[2][1] = fmaf((iv).z, (wv).y, acc[2][1]); \
    acc[2][2] = fmaf((iv).z, (wv).z, acc[2][2]); acc[2][3] = fmaf((iv).z, (wv).w, acc[2][3]); \
    acc[3][0] = fmaf((iv).w, (wv).x, acc[3][0]); acc[3][1] = fmaf((iv).w, (wv).y, acc[3][1]); \
    acc[3][2] = fmaf((iv).w, (wv).z, acc[3][2]); acc[3][3] = fmaf((iv).w, (wv).w, acc[3][3]); \
} while (0)

__device__ __forceinline__ unsigned ldA(const unsigned* p) {
    return __hip_atomic_load(p, __ATOMIC_RELAXED, __HIP_MEMORY_SCOPE_AGENT);
}
__device__ __forceinline__ void stRel(unsigned* p, unsigned v) {
    __hip_atomic_store(p, v, __ATOMIC_RELEASE, __HIP_MEMORY_SCOPE_AGENT);
}

__device__ __forceinline__ void comp_chunk(const float* __restrict__ ib,
                                           const float* __restrict__ wl,
                                           float (&acc)[4][4], int ks, int bg44, int cg4) {
    #pragma unroll
    for (int i = 0; i < 8; ++i) {
        int k = 4 * i + ks;
        float4 iv = *(const float4*)(ib + k * 64 + bg44);
        float4 wv = *(const float4*)(wl + k * 16 + cg4);
        FMA16(iv, wv);
    }
}

__global__ __launch_bounds__(NTHR) void rnn_kernel(
    const float* __restrict__ strokes, const float* __restrict__ trans,
    const float* __restrict__ Wx, const float* __restrict__ Wh,
    const float* __restrict__ bias, const float* __restrict__ Wd,
    const float* __restrict__ bd, float* __restrict__ out,
    float* __restrict__ hbuf, float* __restrict__ wbufT, float* __restrict__ hT,
    unsigned* __restrict__ cnt) {

    extern __shared__ float smem[];
    float* Wl    = smem + SM_WL;
    float* xlds  = smem + SM_XLDS;
    float* zbuf  = smem + SM_ZBUF;
    float* cst   = smem + SM_CST;
    float* kap   = smem + SM_KAP;
    float* yl    = smem + SM_YL;
    float* wf    = smem + SM_WF;
    float* wpart = smem + SM_WPART;

    const int tid  = threadIdx.x;
    const int bid  = blockIdx.x;
    const int half = bid >> 7;     // batch half
    const int hs   = bid & 127;    // h-slice: h-units hs*4..hs*4+3
    const int lane = tid & 63;
    const int rw   = tid >> 6;     // wave id; waves 0,1 = DMA issuers, wave 3 = poller
    const int bg4  = lane & 15;    // batch group of 4
    const int ks   = lane >> 4;    // K-split 4 (lane bits 4-5)
    const int cg4  = rw * 4;
    const int bg44 = bg4 * 4;

    unsigned* dn_h = cnt + 256 + half * 128;
    unsigned* dn_w = cnt + 512 + half * 64;
    float* wT_half = wbufT + half * (N_ * HB);

    const bool isB = (hs & 1) == 0;
    const int  bB  = half * HB + (hs >> 1);

    // ---- register-resident stage-B weights ----
    float trW[64];
    float trT[64];
    #pragma unroll
    for (int j = 0; j < 64; ++j) { trW[j] = 0.f; trT[j] = 0.f; }
    if (isB) {
        if (tid < 240) {
            const int col = tid >> 3, seg = tid & 7;
            const float* wdp = Wd + (size_t)seg * 64 * 30 + col;
            #pragma unroll
            for (int j = 0; j < 64; ++j) trW[j] = wdp[j * 30];
        }
        if (tid < 160) {
            const int s2 = (tid >= 80) ? 1 : 0;
            const int n  = tid - 80 * s2;
            const float* tp = trans + (size_t)bB * (U_ * N_) + (size_t)(s2 * 64) * N_ + n;
            #pragma unroll
            for (int j = 0; j < 64; ++j) trT[j] = tp[j * N_];
        }
    }

    // ---- init: weights (permuted K), zero state ----
    for (int idx = tid; idx < KTOT * 16; idx += NTHR) {
        int kk = idx >> 4, cc = idx & 15;
        int col = (cc >> 2) * 512 + hs * 4 + (cc & 3);
        float v;
        if (kk < 512)      v = Wh[kk * 2048 + col];
        else if (kk < 592) v = Wx[(3 + kk - 512) * 2048 + col];
        else               v = Wx[(kk - 592) * 2048 + col];
        Wl[idx] = v;
    }
    for (int i = tid; i < 256; i += NTHR) cst[i] = 0.f;
    if (tid < M_) kap[tid] = 0.f;
    for (int i = bid * NTHR + tid; i < 2 * H_ * HB + 2 * N_ * HB; i += NBLK * NTHR) {
        if (i < 2 * H_ * HB) hbuf[i] = 0.f;
        else wbufT[i - 2 * H_ * HB] = 0.f;
    }
    __syncthreads();
    if (tid == 0) {
        __threadfence();
        atomicAdd(&cnt[128], 1u);
        while (__hip_atomic_load(&cnt[128], __ATOMIC_RELAXED, __HIP_MEMORY_SCOPE_AGENT) < (unsigned)NBLK)
            __builtin_amdgcn_s_sleep(1);
        __threadfence();
    }
    __syncthreads();

    for (int t = 0; t < T_; ++t) {
        const float* hR = hbuf + ((t & 1) * 2 + half) * (H_ * HB);
        float*       hW = hbuf + (((t + 1) & 1) * 2 + half) * (H_ * HB);

        // ---- wave 3: x-row staging + h_{t-1} wait + acquire fence ----
        if (tid >= 192) {
            const int l3 = tid - 192;
            const float* sp = strokes + (size_t)(half * HB + l3) * (T_ * 3) + t * 3;
            float x0 = sp[0], x1 = sp[1], x2 = sp[2];
            const unsigned tgt = (unsigned)t;
            for (;;) {
                unsigned v0 = ldA(dn_h + l3);
                unsigned v1 = ldA(dn_h + 64 + l3);
                if (!__any((v0 < tgt) | (v1 < tgt))) break;
                __builtin_amdgcn_s_sleep(1);
            }
            __builtin_amdgcn_fence(__ATOMIC_ACQUIRE, "agent");
            xlds[l3] = x0; xlds[64 + l3] = x1; xlds[128 + l3] = x2;
        }
        __syncthreads();   // full drain OK here (all store-queues empty -> release-correct too)

        float acc[4][4];
        #pragma unroll
        for (int a = 0; a < 4; ++a)
            #pragma unroll
            for (int b2 = 0; b2 < 4; ++b2) acc[a][b2] = 0.f;

        // ---- DMA issue helpers (waves 0,1: 4 GLOAD16 = 16 rows each per chunk) ----
        #define ISSUE_H(tc) do { if (rw < 2) { \
            const float* s_ = hR + (tc) * 2048 + rw * 1024 + lane * 4; \
            float* d_ = smem + SM_INPT + ((tc) & 7) * 2048 + rw * 1024; \
            GLOAD16(s_,       d_); \
            GLOAD16(s_ + 256, d_ + 256); \
            GLOAD16(s_ + 512, d_ + 512); \
            GLOAD16(s_ + 768, d_ + 768); } } while (0)
        #define ISSUE_W(tc) do { if (rw < 2) { \
            const float* s_ = wT_half + ((tc) - 16) * 2048 + rw * 1024 + lane * 4; \
            float* d_ = smem + SM_INPT + ((tc) & 7) * 2048 + rw * 1024; \
            GLOAD16(s_,       d_); \
            GLOAD16(s_ + 256, d_ + 256); \
            GLOAD16(s_ + 512, d_ + 512); \
            GLOAD16(s_ + 768, d_ + 768); } } while (0)
        #define ISSUE_W18() do { if (rw < 2) { \
            const float* s_ = wT_half + 4096 + rw * 512 + lane * 4; \
            float* d_ = smem + SM_INPT + 2 * 2048 + rw * 512; \
            GLOAD16(s_,       d_); \
            GLOAD16(s_ + 256, d_ + 256); } } while (0)
        #define CH(c, W) do { WAITV(W); BARX(); \
            comp_chunk(smem + SM_INPT + ((c) & 7) * 2048, Wl + (c) * 512, acc, ks, bg44, cg4); } while (0)

        // ---- prologue: 7 chunks in flight (28 loads/wave) ----
        ISSUE_H(0); ISSUE_H(1); ISSUE_H(2); ISSUE_H(3);
        ISSUE_H(4); ISSUE_H(5); ISSUE_H(6);

        // ---- chunks 0..9: steady state, 7-deep, counted vmcnt, raw barriers ----
        #pragma unroll 1
        for (int c = 0; c < 10; ++c) {
            WAITV(24);
            BARX();
            if (c <= 8) ISSUE_H(c + 7);
            comp_chunk(smem + SM_INPT + (c & 7) * 2048, Wl + c * 512, acc, ks, bg44, cg4);
        }
        CH(10, 20);
        CH(11, 16);
        CH(12, 12);
        CH(13, 8);

        // ---- w-gate (wave 3 polls; no DMA drain) then issue w-chunks ----
        if (tid >= 192) {
            const int l3 = tid - 192;
            const unsigned tgt = (unsigned)t;
            for (;;) {
                unsigned v0 = ldA(dn_w + l3);
                if (!__any(v0 < tgt)) break;
                __builtin_amdgcn_s_sleep(1);
            }
            __builtin_amdgcn_fence(__ATOMIC_ACQUIRE, "agent");
        }
        BARX();
        ISSUE_W(16); ISSUE_W(17); ISSUE_W18();

        CH(14, 14);
        CH(15, 10);
        CH(16, 6);
        CH(17, 2);

        // ---- chunk 18 tail: w rows 64..79 from buf, x rows from xlds ----
        WAITV(0);
        BARX();
        {
            const float* ib = smem + SM_INPT + 2 * 2048;
            const float* wl = Wl + 18 * 512;
            for (int i = 0; i < 5; ++i) {
                int k = 4 * i + ks;
                if (k < 19) {
                    float4 iv;
                    if (k < 16) iv = *(const float4*)(ib + k * 64 + bg44);
                    else        iv = *(const float4*)(xlds + (k - 16) * 64 + bg44);
                    float4 wv = *(const float4*)(wl + k * 16 + cg4);
                    FMA16(iv, wv);
                }
            }
        }

        // ---- cross-K reduce (lane bits 4,5) + stash z ----
        #pragma unroll
        for (int bb = 0; bb < 4; ++bb) {
            #pragma unroll
            for (int cc2 = 0; cc2 < 4; ++cc2) {
                float v = acc[bb][cc2];
                v += __shfl_xor(v, 16, 64);
                v += __shfl_xor(v, 32, 64);
                acc[bb][cc2] = v;
            }
            if (ks == 0)
                *(float4*)&zbuf[(bg44 + bb) * 20 + cg4] =
                    make_float4(acc[bb][0], acc[bb][1], acc[bb][2], acc[bb][3]);
        }
        __syncthreads();

        // ---- LSTM pointwise: thread = (b, jl) ----
        {
            int b = tid & 63, jl = tid >> 6;
            int colb = hs * 4 + jl;
            float zi = zbuf[b * 20 + 0  + jl] + bias[colb];
            float zf = zbuf[b * 20 + 4  + jl] + bias[512 + colb];
            float zg = zbuf[b * 20 + 8  + jl] + bias[1024 + colb];
            float zo = zbuf[b * 20 + 12 + jl] + bias[1536 + colb];
            float co = cst[b * 4 + jl];
            float si = 1.f / (1.f + expf(-zi));
            float sf = 1.f / (1.f + expf(-zf));
            float so = 1.f / (1.f + expf(-zo));
            float cn = sf * co + si * tanhf(zg);
            float hn = so * tanhf(cn);
            cst[b * 4 + jl] = cn;
            hW[colb * 64 + b] = hn;                             // [j][b] for GEMM staging
            hT[(size_t)(half * HB + b) * 512 + colb] = hn;      // [b][j] for stage B
        }
        __syncthreads();   // drains every wave's h stores -> release below is correct
        if (tid == 0) stRel(dn_h + hs, (unsigned)(t + 1));       // release h_t

        // ---- stage B: attention ----
        if (isB) {
            if (tid < 64) {                // wait ALL h_t of this half (wave 0: vmcnt clean)
                const unsigned tgt = (unsigned)(t + 1);
                for (;;) {
                    unsigned v0 = ldA(dn_h + tid);
                    unsigned v1 = ldA(dn_h + 64 + tid);
                    if (!__any((v0 < tgt) | (v1 < tgt))) break;
                    __builtin_amdgcn_s_sleep(1);
                }
                __builtin_amdgcn_fence(__ATOMIC_ACQUIRE, "agent");
            }
            __syncthreads();
            if (tid < 128)   // coalesced 2KB h-column load
                ((float4*)zbuf)[tid] = ((const float4*)(hT + (size_t)bB * 512))[tid];
            __syncthreads();
            if (tid < 240) {                       // y = h @ Wd from registers
                int seg = tid & 7;
                const float* hp = zbuf + seg * 64;
                float s = 0.f;
                #pragma unroll
                for (int jj = 0; jj < 64; ++jj) s = fmaf(hp[jj], trW[jj], s);
                s += __shfl_down(s, 4, 8);
                s += __shfl_down(s, 2, 8);
                s += __shfl_down(s, 1, 8);
                if (seg == 0) yl[tid >> 3] = s;
            }
            __syncthreads();
            if (tid < 30) {
                float e = expf(yl[tid] + bd[tid]);
                yl[tid] = e;
                if (tid >= 20) kap[tid - 20] += e;
            }
            __syncthreads();
            if (tid <= U_) {
                float u = (float)tid, s = 0.f;
                #pragma unroll
                for (int m = 0; m < M_; ++m) {
                    float d = kap[m] - u;
                    s += yl[m] * expf(-yl[10 + m] * d * d);
                }
                wf[tid] = s;
            }
            __syncthreads();
            // w = wfull[:128] @ trans[b] from registers: 2 ordered 64-term segments
            if (tid < 160) {
                const int s2 = (tid >= 80) ? 1 : 0;
                const int n  = tid - 80 * s2;
                const float* wp = wf + s2 * 64;
                float s = 0.f;
                #pragma unroll
                for (int u = 0; u < 64; ++u) s = fmaf(wp[u], trT[u], s);
                wpart[s2 * 80 + n] = s;
            }
            __syncthreads();
            float* op = out + ((size_t)bB * T_ + t) * 593;
            if (tid < N_) {
                float s = wpart[tid] + wpart[80 + tid];
                op[512 + tid] = s;
                wT_half[tid * 64 + (bB & 63)] = s;
            }
            __syncthreads();
            if (tid == 0) stRel(dn_w + (hs >> 1), (unsigned)(t + 1));   // release w_t EARLY

            // non-critical tail
            if (tid < 64) {
                float v = wf[tid]; int ii = tid;
                float v2 = wf[tid + 64];
                if (v2 > v) { v = v2; ii = tid + 64; }
                #pragma unroll
                for (int s2 = 32; s2 >= 1; s2 >>= 1) {
                    float ov = __shfl_down(v, s2, 64);
                    int   oi = __shfl_down(ii, s2, 64);
                    if (ov > v) { v = ov; ii = oi; }
                }
                if (tid == 0) {
                    if (wf[128] > v) ii = 128;
                    op[592] = (float)ii;
                }
            }
            for (int j = tid; j < H_; j += NTHR) op[j] = zbuf[j];
        }
        #undef ISSUE_H
        #undef ISSUE_W
        #undef ISSUE_W18
        #undef CH
    }
}

extern "C" void kernel_launch(void* const* d_in, const int* in_sizes, int n_in,
                              void* d_out, int out_size, void* d_ws, size_t ws_size,
                              hipStream_t stream) {
    const float* strokes = (const float*)d_in[0];
    const float* trans   = (const float*)d_in[1];
    // d_in[2] = enumerated (arange, recomputed in-kernel)
    const float* Wx      = (const float*)d_in[3];
    const float* Wh      = (const float*)d_in[4];
    const float* bias    = (const float*)d_in[5];
    const float* Wd      = (const float*)d_in[6];
    const float* bd      = (const float*)d_in[7];
    float* out = (float*)d_out;

    unsigned* cnt = (unsigned*)d_ws;                       // 4 KB: [128]=init, [256..511]=dn_h, [512..639]=dn_w
    float* hbuf  = (float*)((char*)d_ws + 4096);           // [par][half][512][64] 512 KB
    float* wbufT = hbuf + 2 * 2 * H_ * HB;                 // [half][80][64] 40 KB
    float* hT    = wbufT + 2 * N_ * HB;                    // [128][512] 256 KB

    static bool attr_set = false;
    if (!attr_set) {
        hipFuncSetAttribute((const void*)rnn_kernel,
                            hipFuncAttributeMaxDynamicSharedMemorySize, SMEM_BYTES);
        attr_set = true;
    }

    hipMemsetAsync(d_ws, 0, 4096, stream);                 // reset counters/slots (ws is poisoned)
    hipLaunchKernelGGL(rnn_kernel, dim3(NBLK), dim3(NTHR), SMEM_BYTES, stream,
                       strokes, trans, Wx, Wh, bias, Wd, bd, out, hbuf, wbufT, hT, cnt);
}

// Round 5
// 16749.606 us; speedup vs baseline: 2.8012x; 2.8012x over previous
//
#include <hip/hip_runtime.h>
#include <math.h>

#define NBLK 256
#define NTHR 256
#define HB 64      // batches per half
#define T_ 512
#define U_ 128
#define N_ 80
#define H_ 512
#define M_ 10
#define KTOT 595   // K order: [h 0..511][w 0..79][x 0..2]

// ---- dynamic-LDS layout (float offsets) ----
#define SM_INPT  0        // 8 buffers x 2048 floats (8 x 8KB) = 65536 B
#define SM_WL    16384    // 9520 floats (38080 B) weight slice, permuted K
#define SM_XLDS  25904    // 192 floats: x rows [3][64]
#define SM_ZBUF  26096    // 1280 floats: z / h-column in stage B
#define SM_CST   27376    // 256 floats: c-state
#define SM_KAP   27632    // 16
#define SM_YL    27648    // 32
#define SM_WF    27680    // 132 (U_+1)
#define SM_WPART 27812    // 160
#define SM_TRT   27972    // 10240 floats: trans[bB] slice [128][80] (41KB, block-const)
#define SM_FLOATS 38212
#define SMEM_BYTES (SM_FLOATS * 4)   // 152848 B  (<= 160KB/CU)

typedef __attribute__((address_space(1))) const unsigned int* gp1_t;
typedef __attribute__((address_space(3))) unsigned int* lp3_t;
// width-16 global->LDS DMA: lane i writes ldsbase + i*16, reads gptr + i*16
#define GLOAD16(gp, lp) __builtin_amdgcn_global_load_lds((gp1_t)(gp), (lp3_t)(lp), 16, 0, 0)

// counted DMA wait (waves 0,1 only — they own ALL DMA issues, so N is exact)
#define WAITV(N) do { if (rw < 2) asm volatile("s_waitcnt vmcnt(" #N ")" ::: "memory"); } while (0)
// raw barrier, no vmcnt drain; memory-asm pins LDS reads / DMA issues on both sides
#define BARX()   do { asm volatile("" ::: "memory"); __builtin_amdgcn_s_barrier(); asm volatile("" ::: "memory"); } while (0)

#define FMA16(iv, wv) do { \
    acc[0][0] = fmaf((iv).x, (wv).x, acc[0][0]); acc[0][1] = fmaf((iv).x, (wv).y, acc[0][1]); \
    acc[0][2] = fmaf((iv).x, (wv).z, acc[0][2]); acc[0][3] = fmaf((iv).x, (wv).w, acc[0][3]); \
    acc[1][0] = fmaf((iv).y, (wv).x, acc[1][0]); acc[1][1] = fmaf((iv).y, (wv).y, acc[1][1]); \
    acc[1][2] = fmaf((iv).y, (wv).z, acc[1][2]); acc[1][3] = fmaf((iv).y, (wv).w, acc[1][3]); \
    acc[2][0] = fmaf((iv).z, (wv).x, acc[2][0]); acc[2][1] = fmaf((iv).z, (wv).y, acc[2][1]); \
    acc[2][2] = fmaf((iv).z, (wv).z, acc[2][2]); acc[2][3] = fmaf((iv).z, (wv).w, acc[2][3]); \
    acc[3][0] = fmaf((iv).w, (wv).x, acc[3][0]); acc[3][1] = fmaf((iv).w, (wv).y, acc[3][1]); \
    acc[3][2] = fmaf((iv).w, (wv).z, acc[3][2]); acc[3][3] = fmaf((iv).w, (wv).w, acc[3][3]); \
} while (0)

__device__ __forceinline__ unsigned ldA(const unsigned* p) {
    return __hip_atomic_load(p, __ATOMIC_RELAXED, __HIP_MEMORY_SCOPE_AGENT);
}
__device__ __forceinline__ void stRel(unsigned* p, unsigned v) {
    __hip_atomic_store(p, v, __ATOMIC_RELEASE, __HIP_MEMORY_SCOPE_AGENT);
}

__device__ __forceinline__ void comp_chunk(const float* __restrict__ ib,
                                           const float* __restrict__ wl,
                                           float (&acc)[4][4], int ks, int bg44, int cg4) {
    // unroll 4 (not 8): halves peak iv/wv live set; per-acc FP order unchanged
    #pragma unroll 4
    for (int i = 0; i < 8; ++i) {
        int k = 4 * i + ks;
        float4 iv = *(const float4*)(ib + k * 64 + bg44);
        float4 wv = *(const float4*)(wl + k * 16 + cg4);
        FMA16(iv, wv);
    }
}

__global__ __launch_bounds__(NTHR) void rnn_kernel(
    const float* __restrict__ strokes, const float* __restrict__ trans,
    const float* __restrict__ Wx, const float* __restrict__ Wh,
    const float* __restrict__ bias, const float* __restrict__ Wd,
    const float* __restrict__ bd, float* __restrict__ out,
    float* __restrict__ hbuf, float* __restrict__ wbufT, float* __restrict__ hT,
    unsigned* __restrict__ cnt) {

    extern __shared__ float smem[];
    float* Wl    = smem + SM_WL;
    float* xlds  = smem + SM_XLDS;
    float* zbuf  = smem + SM_ZBUF;
    float* cst   = smem + SM_CST;
    float* kap   = smem + SM_KAP;
    float* yl    = smem + SM_YL;
    float* wf    = smem + SM_WF;
    float* wpart = smem + SM_WPART;
    float* tlds  = smem + SM_TRT;

    const int tid  = threadIdx.x;
    const int bid  = blockIdx.x;
    const int half = bid >> 7;     // batch half
    const int hs   = bid & 127;    // h-slice: h-units hs*4..hs*4+3
    const int lane = tid & 63;
    const int rw   = tid >> 6;     // wave id; waves 0,1 = DMA issuers, wave 3 = poller
    const int bg4  = lane & 15;    // batch group of 4
    const int ks   = lane >> 4;    // K-split 4 (lane bits 4-5)
    const int cg4  = rw * 4;
    const int bg44 = bg4 * 4;

    unsigned* dn_h = cnt + 256 + half * 128;
    unsigned* dn_w = cnt + 512 + half * 64;
    float* wT_half = wbufT + half * (N_ * HB);

    const bool isB = (hs & 1) == 0;
    const int  bB  = half * HB + (hs >> 1);

    // ---- register-resident Wd slice (64 VGPR; trans slice lives in LDS now) ----
    float trW[64];
    #pragma unroll
    for (int j = 0; j < 64; ++j) trW[j] = 0.f;
    if (isB) {
        if (tid < 240) {
            const int col = tid >> 3, seg = tid & 7;
            const float* wdp = Wd + (size_t)seg * 64 * 30 + col;
            #pragma unroll
            for (int j = 0; j < 64; ++j) trW[j] = wdp[j * 30];
        }
        // trans[bB] slice -> LDS, once (block-const, immune to per-step cache inval)
        const float* tsrc = trans + (size_t)bB * (U_ * N_);
        for (int i = tid; i < U_ * N_; i += NTHR) tlds[i] = tsrc[i];
    }

    // ---- init: weights (permuted K), zero state ----
    for (int idx = tid; idx < KTOT * 16; idx += NTHR) {
        int kk = idx >> 4, cc = idx & 15;
        int col = (cc >> 2) * 512 + hs * 4 + (cc & 3);
        float v;
        if (kk < 512)      v = Wh[kk * 2048 + col];
        else if (kk < 592) v = Wx[(3 + kk - 512) * 2048 + col];
        else               v = Wx[(kk - 592) * 2048 + col];
        Wl[idx] = v;
    }
    for (int i = tid; i < 256; i += NTHR) cst[i] = 0.f;
    if (tid < M_) kap[tid] = 0.f;
    for (int i = bid * NTHR + tid; i < 2 * H_ * HB + 2 * N_ * HB; i += NBLK * NTHR) {
        if (i < 2 * H_ * HB) hbuf[i] = 0.f;
        else wbufT[i - 2 * H_ * HB] = 0.f;
    }
    __syncthreads();
    if (tid == 0) {
        __threadfence();
        atomicAdd(&cnt[128], 1u);
        while (__hip_atomic_load(&cnt[128], __ATOMIC_RELAXED, __HIP_MEMORY_SCOPE_AGENT) < (unsigned)NBLK)
            __builtin_amdgcn_s_sleep(1);
        __threadfence();
    }
    __syncthreads();

    for (int t = 0; t < T_; ++t) {
        const float* hR = hbuf + ((t & 1) * 2 + half) * (H_ * HB);
        float*       hW = hbuf + (((t + 1) & 1) * 2 + half) * (H_ * HB);

        // ---- wave 3: x-row staging + h_{t-1} wait + acquire fence ----
        if (tid >= 192) {
            const int l3 = tid - 192;
            const float* sp = strokes + (size_t)(half * HB + l3) * (T_ * 3) + t * 3;
            float x0 = sp[0], x1 = sp[1], x2 = sp[2];
            const unsigned tgt = (unsigned)t;
            for (;;) {
                unsigned v0 = ldA(dn_h + l3);
                unsigned v1 = ldA(dn_h + 64 + l3);
                if (!__any((v0 < tgt) | (v1 < tgt))) break;
                __builtin_amdgcn_s_sleep(1);
            }
            __builtin_amdgcn_fence(__ATOMIC_ACQUIRE, "agent");
            xlds[l3] = x0; xlds[64 + l3] = x1; xlds[128 + l3] = x2;
        }
        __syncthreads();   // full drain OK here (all store-queues empty -> release-correct too)

        float acc[4][4];
        #pragma unroll
        for (int a = 0; a < 4; ++a)
            #pragma unroll
            for (int b2 = 0; b2 < 4; ++b2) acc[a][b2] = 0.f;

        // ---- DMA issue helpers (waves 0,1: 4 GLOAD16 = 16 rows each per chunk) ----
        #define ISSUE_H(tc) do { if (rw < 2) { \
            const float* s_ = hR + (tc) * 2048 + rw * 1024 + lane * 4; \
            float* d_ = smem + SM_INPT + ((tc) & 7) * 2048 + rw * 1024; \
            GLOAD16(s_,       d_); \
            GLOAD16(s_ + 256, d_ + 256); \
            GLOAD16(s_ + 512, d_ + 512); \
            GLOAD16(s_ + 768, d_ + 768); } } while (0)
        #define ISSUE_W(tc) do { if (rw < 2) { \
            const float* s_ = wT_half + ((tc) - 16) * 2048 + rw * 1024 + lane * 4; \
            float* d_ = smem + SM_INPT + ((tc) & 7) * 2048 + rw * 1024; \
            GLOAD16(s_,       d_); \
            GLOAD16(s_ + 256, d_ + 256); \
            GLOAD16(s_ + 512, d_ + 512); \
            GLOAD16(s_ + 768, d_ + 768); } } while (0)
        #define ISSUE_W18() do { if (rw < 2) { \
            const float* s_ = wT_half + 4096 + rw * 512 + lane * 4; \
            float* d_ = smem + SM_INPT + 2 * 2048 + rw * 512; \
            GLOAD16(s_,       d_); \
            GLOAD16(s_ + 256, d_ + 256); } } while (0)
        #define CH(c, W) do { WAITV(W); BARX(); \
            comp_chunk(smem + SM_INPT + ((c) & 7) * 2048, Wl + (c) * 512, acc, ks, bg44, cg4); } while (0)

        // ---- prologue: 7 chunks in flight (28 loads/wave) ----
        ISSUE_H(0); ISSUE_H(1); ISSUE_H(2); ISSUE_H(3);
        ISSUE_H(4); ISSUE_H(5); ISSUE_H(6);

        // ---- chunks 0..9: steady state, 7-deep, counted vmcnt, raw barriers ----
        #pragma unroll 1
        for (int c = 0; c < 10; ++c) {
            WAITV(24);
            BARX();
            if (c <= 8) ISSUE_H(c + 7);
            comp_chunk(smem + SM_INPT + (c & 7) * 2048, Wl + c * 512, acc, ks, bg44, cg4);
        }
        CH(10, 20);
        CH(11, 16);
        CH(12, 12);
        CH(13, 8);

        // ---- w-gate (wave 3 polls; no DMA drain) then issue w-chunks ----
        if (tid >= 192) {
            const int l3 = tid - 192;
            const unsigned tgt = (unsigned)t;
            for (;;) {
                unsigned v0 = ldA(dn_w + l3);
                if (!__any(v0 < tgt)) break;
                __builtin_amdgcn_s_sleep(1);
            }
            __builtin_amdgcn_fence(__ATOMIC_ACQUIRE, "agent");
        }
        BARX();
        ISSUE_W(16); ISSUE_W(17); ISSUE_W18();

        CH(14, 14);
        CH(15, 10);
        CH(16, 6);
        CH(17, 2);

        // ---- chunk 18 tail: w rows 64..79 from buf, x rows from xlds ----
        WAITV(0);
        BARX();
        {
            const float* ib = smem + SM_INPT + 2 * 2048;
            const float* wl = Wl + 18 * 512;
            for (int i = 0; i < 5; ++i) {
                int k = 4 * i + ks;
                if (k < 19) {
                    float4 iv;
                    if (k < 16) iv = *(const float4*)(ib + k * 64 + bg44);
                    else        iv = *(const float4*)(xlds + (k - 16) * 64 + bg44);
                    float4 wv = *(const float4*)(wl + k * 16 + cg4);
                    FMA16(iv, wv);
                }
            }
        }

        // ---- cross-K reduce (lane bits 4,5) + stash z ----
        #pragma unroll
        for (int bb = 0; bb < 4; ++bb) {
            #pragma unroll
            for (int cc2 = 0; cc2 < 4; ++cc2) {
                float v = acc[bb][cc2];
                v += __shfl_xor(v, 16, 64);
                v += __shfl_xor(v, 32, 64);
                acc[bb][cc2] = v;
            }
            if (ks == 0)
                *(float4*)&zbuf[(bg44 + bb) * 20 + cg4] =
                    make_float4(acc[bb][0], acc[bb][1], acc[bb][2], acc[bb][3]);
        }
        __syncthreads();

        // ---- LSTM pointwise: thread = (b, jl) ----
        {
            int b = tid & 63, jl = tid >> 6;
            int colb = hs * 4 + jl;
            float zi = zbuf[b * 20 + 0  + jl] + bias[colb];
            float zf = zbuf[b * 20 + 4  + jl] + bias[512 + colb];
            float zg = zbuf[b * 20 + 8  + jl] + bias[1024 + colb];
            float zo = zbuf[b * 20 + 12 + jl] + bias[1536 + colb];
            float co = cst[b * 4 + jl];
            float si = 1.f / (1.f + expf(-zi));
            float sf = 1.f / (1.f + expf(-zf));
            float so = 1.f / (1.f + expf(-zo));
            float cn = sf * co + si * tanhf(zg);
            float hn = so * tanhf(cn);
            cst[b * 4 + jl] = cn;
            hW[colb * 64 + b] = hn;                             // [j][b] for GEMM staging
            hT[(size_t)(half * HB + b) * 512 + colb] = hn;      // [b][j] for stage B
        }
        __syncthreads();   // drains every wave's h stores -> release below is correct
        if (tid == 0) stRel(dn_h + hs, (unsigned)(t + 1));       // release h_t

        // ---- stage B: attention ----
        if (isB) {
            if (tid < 64) {                // wait ALL h_t of this half (wave 0: vmcnt clean)
                const unsigned tgt = (unsigned)(t + 1);
                for (;;) {
                    unsigned v0 = ldA(dn_h + tid);
                    unsigned v1 = ldA(dn_h + 64 + tid);
                    if (!__any((v0 < tgt) | (v1 < tgt))) break;
                    __builtin_amdgcn_s_sleep(1);
                }
                __builtin_amdgcn_fence(__ATOMIC_ACQUIRE, "agent");
            }
            __syncthreads();
            if (tid < 128)   // coalesced 2KB h-column load
                ((float4*)zbuf)[tid] = ((const float4*)(hT + (size_t)bB * 512))[tid];
            __syncthreads();
            if (tid < 240) {                       // y = h @ Wd from registers
                int seg = tid & 7;
                const float* hp = zbuf + seg * 64;
                float s = 0.f;
                #pragma unroll
                for (int jj = 0; jj < 64; ++jj) s = fmaf(hp[jj], trW[jj], s);
                s += __shfl_down(s, 4, 8);
                s += __shfl_down(s, 2, 8);
                s += __shfl_down(s, 1, 8);
                if (seg == 0) yl[tid >> 3] = s;
            }
            __syncthreads();
            if (tid < 30) {
                float e = expf(yl[tid] + bd[tid]);
                yl[tid] = e;
                if (tid >= 20) kap[tid - 20] += e;
            }
            __syncthreads();
            if (tid <= U_) {
                float u = (float)tid, s = 0.f;
                #pragma unroll
                for (int m = 0; m < M_; ++m) {
                    float d = kap[m] - u;
                    s += yl[m] * expf(-yl[10 + m] * d * d);
                }
                wf[tid] = s;
            }
            __syncthreads();
            // w = wfull[:128] @ trans[b] from LDS: 2 ordered 64-term segments (same order)
            if (tid < 160) {
                const int s2 = (tid >= 80) ? 1 : 0;
                const int n  = tid - 80 * s2;
                const float* wp = wf + s2 * 64;
                const float* tp = tlds + (size_t)(s2 * 64) * N_ + n;
                float s = 0.f;
                #pragma unroll 8
                for (int u = 0; u < 64; ++u) s = fmaf(wp[u], tp[u * N_], s);
                wpart[s2 * 80 + n] = s;
            }
            __syncthreads();
            float* op = out + ((size_t)bB * T_ + t) * 593;
            if (tid < N_) {
                float s = wpart[tid] + wpart[80 + tid];
                op[512 + tid] = s;
                wT_half[tid * 64 + (bB & 63)] = s;
            }
            __syncthreads();
            if (tid == 0) stRel(dn_w + (hs >> 1), (unsigned)(t + 1));   // release w_t EARLY

            // non-critical tail
            if (tid < 64) {
                float v = wf[tid]; int ii = tid;
                float v2 = wf[tid + 64];
                if (v2 > v) { v = v2; ii = tid + 64; }
                #pragma unroll
                for (int s2 = 32; s2 >= 1; s2 >>= 1) {
                    float ov = __shfl_down(v, s2, 64);
                    int   oi = __shfl_down(ii, s2, 64);
                    if (ov > v) { v = ov; ii = oi; }
                }
                if (tid == 0) {
                    if (wf[128] > v) ii = 128;
                    op[592] = (float)ii;
                }
            }
            for (int j = tid; j < H_; j += NTHR) op[j] = zbuf[j];
        }
        #undef ISSUE_H
        #undef ISSUE_W
        #undef ISSUE_W18
        #undef CH
    }
}

extern "C" void kernel_launch(void* const* d_in, const int* in_sizes, int n_in,
                              void* d_out, int out_size, void* d_ws, size_t ws_size,
                              hipStream_t stream) {
    const float* strokes = (const float*)d_in[0];
    const float* trans   = (const float*)d_in[1];
    // d_in[2] = enumerated (arange, recomputed in-kernel)
    const float* Wx      = (const float*)d_in[3];
    const float* Wh      = (const float*)d_in[4];
    const float* bias    = (const float*)d_in[5];
    const float* Wd      = (const float*)d_in[6];
    const float* bd      = (const float*)d_in[7];
    float* out = (float*)d_out;

    unsigned* cnt = (unsigned*)d_ws;                       // 4 KB: [128]=init, [256..511]=dn_h, [512..639]=dn_w
    float* hbuf  = (float*)((char*)d_ws + 4096);           // [par][half][512][64] 512 KB
    float* wbufT = hbuf + 2 * 2 * H_ * HB;                 // [half][80][64] 40 KB
    float* hT    = wbufT + 2 * N_ * HB;                    // [128][512] 256 KB

    static bool attr_set = false;
    if (!attr_set) {
        hipFuncSetAttribute((const void*)rnn_kernel,
                            hipFuncAttributeMaxDynamicSharedMemorySize, SMEM_BYTES);
        attr_set = true;
    }

    hipMemsetAsync(d_ws, 0, 4096, stream);                 // reset counters/slots (ws is poisoned)
    hipLaunchKernelGGL(rnn_kernel, dim3(NBLK), dim3(NTHR), SMEM_BYTES, stream,
                       strokes, trans, Wx, Wh, bias, Wd, bd, out, hbuf, wbufT, hT, cnt);
}

// Round 6
// 12455.662 us; speedup vs baseline: 3.7669x; 1.3447x over previous
//
#include <hip/hip_runtime.h>
#include <math.h>

#define NBLK 256
#define NTHR 256
#define HB 64      // batches per half
#define T_ 512
#define U_ 128
#define N_ 80
#define H_ 512
#define M_ 10
#define KTOT 595   // K order: [h 0..511][w 0..79][x 0..2]

// ---- dynamic-LDS layout (float offsets) ----
#define SM_INPT  0        // 8 buffers x 2048 floats (8 x 8KB) = 65536 B
#define SM_WL    16384    // 9520 floats (38080 B) weight slice, permuted K
#define SM_XLDS  25904    // 192 floats: x rows [3][64]
#define SM_ZBUF  26096    // 1280 floats: z / h-column in stage B
#define SM_CST   27376    // 256 floats: c-state
#define SM_KAP   27632    // 16
#define SM_YL    27648    // 32
#define SM_WF    27680    // 132 (U_+1)
#define SM_WPART 27812    // 160
#define SM_TRT   27972    // 10240 floats: trans[bB] slice [128][80] (41KB, block-const)
#define SM_FLOATS 38212
#define SMEM_BYTES (SM_FLOATS * 4)   // 152848 B  (<= 160KB/CU)

typedef __attribute__((address_space(1))) const unsigned int* gp1_t;
typedef __attribute__((address_space(3))) unsigned int* lp3_t;
// width-16 global->LDS DMA: lane i writes ldsbase + i*16, reads gptr + i*16
#define GLOAD16(gp, lp) __builtin_amdgcn_global_load_lds((gp1_t)(gp), (lp3_t)(lp), 16, 0, 0)

// counted DMA wait (waves 0,1 only — they own ALL DMA issues, so N is exact)
#define WAITV(N) do { if (rw < 2) asm volatile("s_waitcnt vmcnt(" #N ")" ::: "memory"); } while (0)
// raw barrier, no vmcnt drain; memory-asm pins LDS reads / DMA issues on both sides
#define BARX()   do { asm volatile("" ::: "memory"); __builtin_amdgcn_s_barrier(); asm volatile("" ::: "memory"); } while (0)

#define FMA16(iv, wv) do { \
    acc[0][0] = fmaf((iv).x, (wv).x, acc[0][0]); acc[0][1] = fmaf((iv).x, (wv).y, acc[0][1]); \
    acc[0][2] = fmaf((iv).x, (wv).z, acc[0][2]); acc[0][3] = fmaf((iv).x, (wv).w, acc[0][3]); \
    acc[1][0] = fmaf((iv).y, (wv).x, acc[1][0]); acc[1][1] = fmaf((iv).y, (wv).y, acc[1][1]); \
    acc[1][2] = fmaf((iv).y, (wv).z, acc[1][2]); acc[1][3] = fmaf((iv).y, (wv).w, acc[1][3]); \
    acc[2][0] = fmaf((iv).z, (wv).x, acc[2][0]); acc[2][1] = fmaf((iv).z, (wv).y, acc[2][1]); \
    acc[2][2] = fmaf((iv).z, (wv).z, acc[2][2]); acc[2][3] = fmaf((iv).z, (wv).w, acc[2][3]); \
    acc[3][0] = fmaf((iv).w, (wv).x, acc[3][0]); acc[3][1] = fmaf((iv).w, (wv).y, acc[3][1]); \
    acc[3][2] = fmaf((iv).w, (wv).z, acc[3][2]); acc[3][3] = fmaf((iv).w, (wv).w, acc[3][3]); \
} while (0)

__device__ __forceinline__ unsigned ldA(const unsigned* p) {
    return __hip_atomic_load(p, __ATOMIC_RELAXED, __HIP_MEMORY_SCOPE_AGENT);
}
__device__ __forceinline__ void stRel(unsigned* p, unsigned v) {
    __hip_atomic_store(p, v, __ATOMIC_RELEASE, __HIP_MEMORY_SCOPE_AGENT);
}
// write-through store (sc1 -> LLC, never dirty in XCD L2): keeps release wbl2 cheap
__device__ __forceinline__ void stG(float* p, float v) {
    __hip_atomic_store(p, v, __ATOMIC_RELAXED, __HIP_MEMORY_SCOPE_AGENT);
}

__device__ __forceinline__ void comp_chunk(const float* __restrict__ ib,
                                           const float* __restrict__ wl,
                                           float (&acc)[4][4], int ks, int bg44, int cg4) {
    // unroll 4 (not 8): halves peak iv/wv live set; per-acc FP order unchanged
    #pragma unroll 4
    for (int i = 0; i < 8; ++i) {
        int k = 4 * i + ks;
        float4 iv = *(const float4*)(ib + k * 64 + bg44);
        float4 wv = *(const float4*)(wl + k * 16 + cg4);
        FMA16(iv, wv);
    }
}

__global__ __launch_bounds__(NTHR) void rnn_kernel(
    const float* __restrict__ strokes, const float* __restrict__ trans,
    const float* __restrict__ Wx, const float* __restrict__ Wh,
    const float* __restrict__ bias, const float* __restrict__ Wd,
    const float* __restrict__ bd, float* __restrict__ out,
    float* __restrict__ hbuf, float* __restrict__ wbufT, float* __restrict__ hT,
    unsigned* __restrict__ cnt) {

    extern __shared__ float smem[];
    float* Wl    = smem + SM_WL;
    float* xlds  = smem + SM_XLDS;
    float* zbuf  = smem + SM_ZBUF;
    float* cst   = smem + SM_CST;
    float* kap   = smem + SM_KAP;
    float* yl    = smem + SM_YL;
    float* wf    = smem + SM_WF;
    float* wpart = smem + SM_WPART;
    float* tlds  = smem + SM_TRT;

    const int tid  = threadIdx.x;
    const int bid  = blockIdx.x;
    const int half = bid >> 7;     // batch half
    const int hs   = bid & 127;    // h-slice: h-units hs*4..hs*4+3
    const int lane = tid & 63;
    const int rw   = tid >> 6;     // wave id; waves 0,1 = DMA issuers, wave 3 = poller
    const int bg4  = lane & 15;    // batch group of 4
    const int ks   = lane >> 4;    // K-split 4 (lane bits 4-5)
    const int cg4  = rw * 4;
    const int bg44 = bg4 * 4;

    unsigned* dn_h = cnt + 256 + half * 128;
    unsigned* dn_w = cnt + 512 + half * 64;
    float* wT_half = wbufT + half * (N_ * HB);

    const bool isB = (hs & 1) == 0;
    const int  bB  = half * HB + (hs >> 1);

    // ---- register-resident Wd slice (64 VGPR; trans slice lives in LDS) ----
    float trW[64];
    #pragma unroll
    for (int j = 0; j < 64; ++j) trW[j] = 0.f;
    if (isB) {
        if (tid < 240) {
            const int col = tid >> 3, seg = tid & 7;
            const float* wdp = Wd + (size_t)seg * 64 * 30 + col;
            #pragma unroll
            for (int j = 0; j < 64; ++j) trW[j] = wdp[j * 30];
        }
        // trans[bB] slice -> LDS, once (block-const, immune to per-step cache inval)
        const float* tsrc = trans + (size_t)bB * (U_ * N_);
        for (int i = tid; i < U_ * N_; i += NTHR) tlds[i] = tsrc[i];
    }

    // ---- init: weights (permuted K), zero state ----
    for (int idx = tid; idx < KTOT * 16; idx += NTHR) {
        int kk = idx >> 4, cc = idx & 15;
        int col = (cc >> 2) * 512 + hs * 4 + (cc & 3);
        float v;
        if (kk < 512)      v = Wh[kk * 2048 + col];
        else if (kk < 592) v = Wx[(3 + kk - 512) * 2048 + col];
        else               v = Wx[(kk - 592) * 2048 + col];
        Wl[idx] = v;
    }
    for (int i = tid; i < 256; i += NTHR) cst[i] = 0.f;
    if (tid < M_) kap[tid] = 0.f;
    for (int i = bid * NTHR + tid; i < 2 * H_ * HB + 2 * N_ * HB; i += NBLK * NTHR) {
        if (i < 2 * H_ * HB) hbuf[i] = 0.f;
        else wbufT[i - 2 * H_ * HB] = 0.f;
    }
    __syncthreads();
    if (tid == 0) {
        __threadfence();
        atomicAdd(&cnt[128], 1u);
        while (__hip_atomic_load(&cnt[128], __ATOMIC_RELAXED, __HIP_MEMORY_SCOPE_AGENT) < (unsigned)NBLK)
            __builtin_amdgcn_s_sleep(1);
        __threadfence();
    }
    __syncthreads();

    for (int t = 0; t < T_; ++t) {
        const float* hR = hbuf + ((t & 1) * 2 + half) * (H_ * HB);
        float*       hW = hbuf + (((t + 1) & 1) * 2 + half) * (H_ * HB);

        // ---- wave 3: x-row staging + h_{t-1} wait + acquire fence ----
        if (tid >= 192) {
            const int l3 = tid - 192;
            const float* sp = strokes + (size_t)(half * HB + l3) * (T_ * 3) + t * 3;
            float x0 = sp[0], x1 = sp[1], x2 = sp[2];
            const unsigned tgt = (unsigned)t;
            for (;;) {
                unsigned v0 = ldA(dn_h + l3);
                unsigned v1 = ldA(dn_h + 64 + l3);
                if (!__any((v0 < tgt) | (v1 < tgt))) break;
                __builtin_amdgcn_s_sleep(1);
            }
            __builtin_amdgcn_fence(__ATOMIC_ACQUIRE, "agent");
            xlds[l3] = x0; xlds[64 + l3] = x1; xlds[128 + l3] = x2;
        }
        __syncthreads();   // full drain OK here (all store-queues empty -> release-correct too)

        float acc[4][4];
        #pragma unroll
        for (int a = 0; a < 4; ++a)
            #pragma unroll
            for (int b2 = 0; b2 < 4; ++b2) acc[a][b2] = 0.f;

        // ---- DMA issue helpers (waves 0,1: 4 GLOAD16 = 16 rows each per chunk) ----
        #define ISSUE_H(tc) do { if (rw < 2) { \
            const float* s_ = hR + (tc) * 2048 + rw * 1024 + lane * 4; \
            float* d_ = smem + SM_INPT + ((tc) & 7) * 2048 + rw * 1024; \
            GLOAD16(s_,       d_); \
            GLOAD16(s_ + 256, d_ + 256); \
            GLOAD16(s_ + 512, d_ + 512); \
            GLOAD16(s_ + 768, d_ + 768); } } while (0)
        #define ISSUE_W(tc) do { if (rw < 2) { \
            const float* s_ = wT_half + ((tc) - 16) * 2048 + rw * 1024 + lane * 4; \
            float* d_ = smem + SM_INPT + ((tc) & 7) * 2048 + rw * 1024; \
            GLOAD16(s_,       d_); \
            GLOAD16(s_ + 256, d_ + 256); \
            GLOAD16(s_ + 512, d_ + 512); \
            GLOAD16(s_ + 768, d_ + 768); } } while (0)
        #define ISSUE_W18() do { if (rw < 2) { \
            const float* s_ = wT_half + 4096 + rw * 512 + lane * 4; \
            float* d_ = smem + SM_INPT + 2 * 2048 + rw * 512; \
            GLOAD16(s_,       d_); \
            GLOAD16(s_ + 256, d_ + 256); } } while (0)
        #define CH(c, W) do { WAITV(W); BARX(); \
            comp_chunk(smem + SM_INPT + ((c) & 7) * 2048, Wl + (c) * 512, acc, ks, bg44, cg4); } while (0)

        // ---- prologue: 7 chunks in flight (28 loads/wave) ----
        ISSUE_H(0); ISSUE_H(1); ISSUE_H(2); ISSUE_H(3);
        ISSUE_H(4); ISSUE_H(5); ISSUE_H(6);

        // ---- chunks 0..9: steady state, 7-deep, counted vmcnt, raw barriers ----
        #pragma unroll 1
        for (int c = 0; c < 10; ++c) {
            WAITV(24);
            BARX();
            if (c <= 8) ISSUE_H(c + 7);
            comp_chunk(smem + SM_INPT + (c & 7) * 2048, Wl + c * 512, acc, ks, bg44, cg4);
        }
        CH(10, 20);
        CH(11, 16);
        CH(12, 12);
        CH(13, 8);

        // ---- w-gate (wave 3 polls; no DMA drain) then issue w-chunks ----
        if (tid >= 192) {
            const int l3 = tid - 192;
            const unsigned tgt = (unsigned)t;
            for (;;) {
                unsigned v0 = ldA(dn_w + l3);
                if (!__any(v0 < tgt)) break;
                __builtin_amdgcn_s_sleep(1);
            }
            __builtin_amdgcn_fence(__ATOMIC_ACQUIRE, "agent");
        }
        BARX();
        ISSUE_W(16); ISSUE_W(17); ISSUE_W18();

        CH(14, 14);
        CH(15, 10);
        CH(16, 6);
        CH(17, 2);

        // ---- chunk 18 tail: w rows 64..79 from buf, x rows from xlds ----
        WAITV(0);
        BARX();
        {
            const float* ib = smem + SM_INPT + 2 * 2048;
            const float* wl = Wl + 18 * 512;
            for (int i = 0; i < 5; ++i) {
                int k = 4 * i + ks;
                if (k < 19) {
                    float4 iv;
                    if (k < 16) iv = *(const float4*)(ib + k * 64 + bg44);
                    else        iv = *(const float4*)(xlds + (k - 16) * 64 + bg44);
                    float4 wv = *(const float4*)(wl + k * 16 + cg4);
                    FMA16(iv, wv);
                }
            }
        }

        // ---- cross-K reduce (lane bits 4,5) + stash z ----
        #pragma unroll
        for (int bb = 0; bb < 4; ++bb) {
            #pragma unroll
            for (int cc2 = 0; cc2 < 4; ++cc2) {
                float v = acc[bb][cc2];
                v += __shfl_xor(v, 16, 64);
                v += __shfl_xor(v, 32, 64);
                acc[bb][cc2] = v;
            }
            if (ks == 0)
                *(float4*)&zbuf[(bg44 + bb) * 20 + cg4] =
                    make_float4(acc[bb][0], acc[bb][1], acc[bb][2], acc[bb][3]);
        }
        __syncthreads();

        // ---- LSTM pointwise: thread = (b, jl); write-through stores keep L2 clean ----
        {
            int b = tid & 63, jl = tid >> 6;
            int colb = hs * 4 + jl;
            float zi = zbuf[b * 20 + 0  + jl] + bias[colb];
            float zf = zbuf[b * 20 + 4  + jl] + bias[512 + colb];
            float zg = zbuf[b * 20 + 8  + jl] + bias[1024 + colb];
            float zo = zbuf[b * 20 + 12 + jl] + bias[1536 + colb];
            float co = cst[b * 4 + jl];
            float si = 1.f / (1.f + expf(-zi));
            float sf = 1.f / (1.f + expf(-zf));
            float so = 1.f / (1.f + expf(-zo));
            float cn = sf * co + si * tanhf(zg);
            float hn = so * tanhf(cn);
            cst[b * 4 + jl] = cn;
            stG(&hW[colb * 64 + b], hn);                             // [j][b] for GEMM staging
            stG(&hT[(size_t)(half * HB + b) * 512 + colb], hn);      // [b][j] for stage B
        }
        __syncthreads();   // drains every wave's h stores -> release below is correct
        if (tid == 0) stRel(dn_h + hs, (unsigned)(t + 1));       // release h_t

        // ---- stage B: attention ----
        if (isB) {
            if (tid < 64) {                // wait ALL h_t of this half (wave 0: vmcnt clean)
                const unsigned tgt = (unsigned)(t + 1);
                for (;;) {
                    unsigned v0 = ldA(dn_h + tid);
                    unsigned v1 = ldA(dn_h + 64 + tid);
                    if (!__any((v0 < tgt) | (v1 < tgt))) break;
                    __builtin_amdgcn_s_sleep(1);
                }
                __builtin_amdgcn_fence(__ATOMIC_ACQUIRE, "agent");
            }
            __syncthreads();
            if (tid < 128)   // coalesced 2KB h-column load
                ((float4*)zbuf)[tid] = ((const float4*)(hT + (size_t)bB * 512))[tid];
            __syncthreads();
            if (tid < 240) {                       // y = h @ Wd from registers
                int seg = tid & 7;
                const float* hp = zbuf + seg * 64;
                float s = 0.f;
                #pragma unroll
                for (int jj = 0; jj < 64; ++jj) s = fmaf(hp[jj], trW[jj], s);
                s += __shfl_down(s, 4, 8);
                s += __shfl_down(s, 2, 8);
                s += __shfl_down(s, 1, 8);
                if (seg == 0) yl[tid >> 3] = s;
            }
            __syncthreads();
            if (tid < 30) {
                float e = expf(yl[tid] + bd[tid]);
                yl[tid] = e;
                if (tid >= 20) kap[tid - 20] += e;
            }
            __syncthreads();
            if (tid <= U_) {
                float u = (float)tid, s = 0.f;
                #pragma unroll
                for (int m = 0; m < M_; ++m) {
                    float d = kap[m] - u;
                    s += yl[m] * expf(-yl[10 + m] * d * d);
                }
                wf[tid] = s;
            }
            __syncthreads();
            // w = wfull[:128] @ trans[b] from LDS: 2 ordered 64-term segments (same order)
            if (tid < 160) {
                const int s2 = (tid >= 80) ? 1 : 0;
                const int n  = tid - 80 * s2;
                const float* wp = wf + s2 * 64;
                const float* tp = tlds + (size_t)(s2 * 64) * N_ + n;
                float s = 0.f;
                #pragma unroll 8
                for (int u = 0; u < 64; ++u) s = fmaf(wp[u], tp[u * N_], s);
                wpart[s2 * 80 + n] = s;
            }
            __syncthreads();
            float* op = out + ((size_t)bB * T_ + t) * 593;
            if (tid < N_) {                        // consumer-visible w only (write-through)
                float s = wpart[tid] + wpart[80 + tid];
                stG(&wT_half[tid * 64 + (bB & 63)], s);
            }
            __syncthreads();
            if (tid == 0) stRel(dn_w + (hs >> 1), (unsigned)(t + 1));   // release w_t EARLY

            // non-critical tail (consumers already unblocked); all write-through
            if (tid < N_) stG(&op[512 + tid], wpart[tid] + wpart[80 + tid]);
            if (tid < 64) {
                float v = wf[tid]; int ii = tid;
                float v2 = wf[tid + 64];
                if (v2 > v) { v = v2; ii = tid + 64; }
                #pragma unroll
                for (int s2 = 32; s2 >= 1; s2 >>= 1) {
                    float ov = __shfl_down(v, s2, 64);
                    int   oi = __shfl_down(ii, s2, 64);
                    if (ov > v) { v = ov; ii = oi; }
                }
                if (tid == 0) {
                    if (wf[128] > v) ii = 128;
                    stG(&op[592], (float)ii);
                }
            }
            for (int j = tid; j < H_; j += NTHR) stG(&op[j], zbuf[j]);
        }
        #undef ISSUE_H
        #undef ISSUE_W
        #undef ISSUE_W18
        #undef CH
    }
}

extern "C" void kernel_launch(void* const* d_in, const int* in_sizes, int n_in,
                              void* d_out, int out_size, void* d_ws, size_t ws_size,
                              hipStream_t stream) {
    const float* strokes = (const float*)d_in[0];
    const float* trans   = (const float*)d_in[1];
    // d_in[2] = enumerated (arange, recomputed in-kernel)
    const float* Wx      = (const float*)d_in[3];
    const float* Wh      = (const float*)d_in[4];
    const float* bias    = (const float*)d_in[5];
    const float* Wd      = (const float*)d_in[6];
    const float* bd      = (const float*)d_in[7];
    float* out = (float*)d_out;

    unsigned* cnt = (unsigned*)d_ws;                       // 4 KB: [128]=init, [256..511]=dn_h, [512..639]=dn_w
    float* hbuf  = (float*)((char*)d_ws + 4096);           // [par][half][512][64] 512 KB
    float* wbufT = hbuf + 2 * 2 * H_ * HB;                 // [half][80][64] 40 KB
    float* hT    = wbufT + 2 * N_ * HB;                    // [128][512] 256 KB

    static bool attr_set = false;
    if (!attr_set) {
        hipFuncSetAttribute((const void*)rnn_kernel,
                            hipFuncAttributeMaxDynamicSharedMemorySize, SMEM_BYTES);
        attr_set = true;
    }

    hipMemsetAsync(d_ws, 0, 4096, stream);                 // reset counters/slots (ws is poisoned)
    hipLaunchKernelGGL(rnn_kernel, dim3(NBLK), dim3(NTHR), SMEM_BYTES, stream,
                       strokes, trans, Wx, Wh, bias, Wd, bd, out, hbuf, wbufT, hT, cnt);
}